// Round 1
// baseline (277.850 us; speedup 1.0000x reference)
//
#include <hip/hip_runtime.h>
#include <stdint.h>

typedef unsigned short u16;
typedef __attribute__((ext_vector_type(8))) short bf16x8;
typedef __attribute__((ext_vector_type(4))) short bf16x4;
typedef __attribute__((ext_vector_type(4))) float f32x4;
typedef __attribute__((ext_vector_type(4))) unsigned short u16x4;

#define S_ 2048
#define E_ 1024

__device__ __forceinline__ u16 f2bf(float f) {
  union { float f; unsigned u; } v; v.f = f;
  unsigned u = v.u;
  unsigned r = (u + 0x7FFFu + ((u >> 16) & 1u)) >> 16;
  return (u16)r;
}
__device__ __forceinline__ float bf2f(u16 h) {
  union { unsigned u; float f; } v; v.u = ((unsigned)h) << 16;
  return v.f;
}

// ---------------- cast f32 -> bf16 (x4 vectorized) ----------------
__global__ void k_cast(const float* __restrict__ in, u16* __restrict__ out, int n4) {
  int i = blockIdx.x * blockDim.x + threadIdx.x;
  if (i >= n4) return;
  float4 v = *((const float4*)in + i);
  u16x4 o;
  o.x = f2bf(v.x); o.y = f2bf(v.y); o.z = f2bf(v.z); o.w = f2bf(v.w);
  *((u16x4*)out + i) = o;
}

// ---------------- 128x128 tile bf16 GEMM: C[M][1024] = A[M][1024] * W[N][K]^T ----------------
// grid.x = M/128, grid.y = 8*nW (weight select = by>>3). outF32 selects epilogue type.
__global__ __launch_bounds__(256) void k_gemm(
    const u16* __restrict__ A,
    const u16* __restrict__ W0, const u16* __restrict__ W1, const u16* __restrict__ W2,
    void* O0, void* O1, void* O2, int outF32)
{
  __shared__ __align__(16) u16 As[128 * 32];
  __shared__ __align__(16) u16 Ws[128 * 32];
  int tid = threadIdx.x;
  int wid = tid >> 6, lane = tid & 63;
  int lg = lane >> 4, lr = lane & 15;
  int wsel = blockIdx.y >> 3, nb = blockIdx.y & 7;
  const u16* W = (wsel == 0) ? W0 : ((wsel == 1) ? W1 : W2);
  void* O = (wsel == 0) ? O0 : ((wsel == 1) ? O1 : O2);
  int m0 = blockIdx.x * 128;
  int n0 = nb * 128;
  int wr = wid >> 1, wc = wid & 1;

  f32x4 acc[4][4];
#pragma unroll
  for (int m = 0; m < 4; m++)
#pragma unroll
    for (int n = 0; n < 4; n++) acc[m][n] = (f32x4){0.f, 0.f, 0.f, 0.f};

  int srow = tid >> 2;
  int scol = (tid & 3) * 8;
  const u16* ag = A + (size_t)(m0 + srow) * 1024 + scol;
  const u16* wg = W + (size_t)(n0 + srow) * 1024 + scol;
  u16* asl = &As[tid * 8];
  u16* wsl = &Ws[tid * 8];

  for (int kt = 0; kt < 1024; kt += 32) {
    bf16x8 a0 = *(const bf16x8*)(ag + kt);
    bf16x8 a1 = *(const bf16x8*)(ag + kt + 64 * 1024);
    bf16x8 w0 = *(const bf16x8*)(wg + kt);
    bf16x8 w1 = *(const bf16x8*)(wg + kt + 64 * 1024);
    __syncthreads();
    *(bf16x8*)asl = a0;
    *(bf16x8*)(asl + 64 * 32) = a1;
    *(bf16x8*)wsl = w0;
    *(bf16x8*)(wsl + 64 * 32) = w1;
    __syncthreads();
    bf16x8 af[4], wf[4];
#pragma unroll
    for (int m = 0; m < 4; m++) af[m] = *(const bf16x8*)&As[(wr * 64 + m * 16 + lr) * 32 + lg * 8];
#pragma unroll
    for (int n = 0; n < 4; n++) wf[n] = *(const bf16x8*)&Ws[(wc * 64 + n * 16 + lr) * 32 + lg * 8];
#pragma unroll
    for (int m = 0; m < 4; m++)
#pragma unroll
      for (int n = 0; n < 4; n++)
        acc[m][n] = __builtin_amdgcn_mfma_f32_16x16x32_bf16(af[m], wf[n], acc[m][n], 0, 0, 0);
  }

#pragma unroll
  for (int m = 0; m < 4; m++) {
    int gr = m0 + wr * 64 + m * 16 + lg * 4;
#pragma unroll
    for (int n = 0; n < 4; n++) {
      int gc = n0 + wc * 64 + n * 16 + lr;
#pragma unroll
      for (int r = 0; r < 4; r++) {
        if (outF32) ((float*)O)[(size_t)(gr + r) * 1024 + gc] = acc[m][n][r];
        else ((u16*)O)[(size_t)(gr + r) * 1024 + gc] = f2bf(acc[m][n][r]);
      }
    }
  }
}

// ---------------- RoPE in place on Q and K ([B,S,E] bf16, pairs) ----------------
__global__ void k_rope(u16* __restrict__ Q, u16* __restrict__ K) {
  int idx = blockIdx.x * blockDim.x + threadIdx.x; // < B*S*512
  int p = idx & 511;
  int srow = idx >> 9;
  int s = srow & (S_ - 1);
  int i = p & 31;
  float ang = (float)s * exp2f(-0.415241012f * (float)i); // theta^(-i/32)
  float sn, c;
  __sincosf(ang, &sn, &c);
  unsigned* qp = (unsigned*)Q + idx;
  unsigned qv = *qp;
  float e = bf2f((u16)(qv & 0xffff)), o = bf2f((u16)(qv >> 16));
  float re = e * c - o * sn, ro = e * sn + o * c;
  *qp = (unsigned)f2bf(re) | ((unsigned)f2bf(ro) << 16);
  unsigned* kp = (unsigned*)K + idx;
  unsigned kv = *kp;
  e = bf2f((u16)(kv & 0xffff)); o = bf2f((u16)(kv >> 16));
  re = e * c - o * sn; ro = e * sn + o * c;
  *kp = (unsigned)f2bf(re) | ((unsigned)f2bf(ro) << 16);
}

// ---------------- causal flash attention ----------------
// grid: x = S/64, y = B*H. 4 waves/block, each wave owns 16 q rows. Zero barriers.
// Swapped scheme: S^T = mfma(K, Q) -> lane owns col q=lr, rows kv=lg*4+j.
__global__ __launch_bounds__(256) void k_attn(
    const u16* __restrict__ Q, const u16* __restrict__ K,
    const u16* __restrict__ V, u16* __restrict__ AO)
{
  int bh = blockIdx.y;
  int wid = threadIdx.x >> 6, lane = threadIdx.x & 63;
  int lg = lane >> 4, lr = lane & 15;
  int qb = 31 - blockIdx.x; // heavy blocks first
  int q0 = qb * 64 + wid * 16;
  size_t base = (size_t)(bh >> 4) * (2048u * 1024u) + (size_t)(bh & 15) * 64;

  const u16* qrow = Q + base + (size_t)(q0 + lr) * 1024 + lg * 8;
  bf16x8 qf0 = *(const bf16x8*)(qrow);
  bf16x8 qf1 = *(const bf16x8*)(qrow + 32);

  float m = -1e30f, lsum = 0.f;
  f32x4 o[4];
#pragma unroll
  for (int c = 0; c < 4; c++) o[c] = (f32x4){0.f, 0.f, 0.f, 0.f};

  int ntile = (q0 >> 4) + 1;
  const u16* kbase = K + base + (size_t)lr * 1024 + lg * 8;
  const u16* vbase = V + base + (size_t)(lg * 4) * 1024 + lr;
  int qg = q0 + lr;

  for (int t = 0; t < ntile; ++t) {
    int kv0 = t * 16;
    const u16* kr = kbase + (size_t)kv0 * 1024;
    bf16x8 kf0 = *(const bf16x8*)kr;
    bf16x8 kf1 = *(const bf16x8*)(kr + 32);
    f32x4 s = (f32x4){0.f, 0.f, 0.f, 0.f};
    s = __builtin_amdgcn_mfma_f32_16x16x32_bf16(kf0, qf0, s, 0, 0, 0);
    s = __builtin_amdgcn_mfma_f32_16x16x32_bf16(kf1, qf1, s, 0, 0, 0);
    if (t == ntile - 1) {
#pragma unroll
      for (int j = 0; j < 4; j++) {
        int kvg = kv0 + lg * 4 + j;
        s[j] = (kvg <= qg) ? s[j] * 0.125f : -1e30f;
      }
    } else {
#pragma unroll
      for (int j = 0; j < 4; j++) s[j] *= 0.125f;
    }
    float tm = fmaxf(fmaxf(s[0], s[1]), fmaxf(s[2], s[3]));
    tm = fmaxf(tm, __shfl_xor(tm, 16));
    tm = fmaxf(tm, __shfl_xor(tm, 32));
    float mn = fmaxf(m, tm);
    float corr = __expf(m - mn);
    m = mn;
    lsum *= corr;
#pragma unroll
    for (int c = 0; c < 4; c++) {
      o[c][0] *= corr; o[c][1] *= corr; o[c][2] *= corr; o[c][3] *= corr;
    }
    float p[4];
#pragma unroll
    for (int j = 0; j < 4; j++) { p[j] = __expf(s[j] - mn); lsum += p[j]; }
    bf16x4 pb;
#pragma unroll
    for (int j = 0; j < 4; j++) pb[j] = (short)f2bf(p[j]);
    const u16* vr = vbase + (size_t)kv0 * 1024;
#pragma unroll
    for (int c = 0; c < 4; c++) {
      bf16x4 va;
#pragma unroll
      for (int j = 0; j < 4; j++) va[j] = (short)vr[(size_t)j * 1024 + c * 16];
      o[c] = __builtin_amdgcn_mfma_f32_16x16x16bf16_1k(va, pb, o[c], 0, 0, 0);
    }
  }

  float lt = lsum + __shfl_xor(lsum, 16);
  lt += __shfl_xor(lt, 32);
  float inv = 1.0f / lt;
  u16* orow = AO + base + (size_t)(q0 + lr) * 1024;
#pragma unroll
  for (int c = 0; c < 4; c++)
#pragma unroll
    for (int r = 0; r < 4; r++)
      orow[c * 16 + lg * 4 + r] = f2bf(o[c][r] * inv);
}

extern "C" void kernel_launch(void* const* d_in, const int* in_sizes, int n_in,
                              void* d_out, int out_size, void* d_ws, size_t ws_size,
                              hipStream_t stream) {
  const float* x = (const float*)d_in[0];
  const float* wq = (const float*)d_in[1];
  const float* wk = (const float*)d_in[2];
  const float* wv = (const float*)d_in[3];
  const float* wo = (const float*)d_in[4];

  char* ws = (char*)d_ws;
  u16* xb  = (u16*)(ws);                 // 8 MiB: x bf16 [4096][1024]
  u16* wqb = (u16*)(ws + 8388608);       // 2 MiB each
  u16* wkb = (u16*)(ws + 10485760);
  u16* wvb = (u16*)(ws + 12582912);
  u16* wob = (u16*)(ws + 14680064);
  u16* Qb  = (u16*)(ws + 16777216);      // 8 MiB each, [B,S,E]
  u16* Kb  = (u16*)(ws + 25165824);
  u16* Vb  = (u16*)(ws + 33554432);
  u16* AO  = (u16*)(ws + 41943040);      // 8 MiB

  k_cast<<<4096, 256, 0, stream>>>(x, xb, 1048576);
  k_cast<<<1024, 256, 0, stream>>>(wq, wqb, 262144);
  k_cast<<<1024, 256, 0, stream>>>(wk, wkb, 262144);
  k_cast<<<1024, 256, 0, stream>>>(wv, wvb, 262144);
  k_cast<<<1024, 256, 0, stream>>>(wo, wob, 262144);

  k_gemm<<<dim3(32, 24), 256, 0, stream>>>(xb, wqb, wkb, wvb, Qb, Kb, Vb, 0);
  k_rope<<<8192, 256, 0, stream>>>(Qb, Kb);
  k_attn<<<dim3(32, 32), 256, 0, stream>>>(Qb, Kb, Vb, AO);
  k_gemm<<<dim3(32, 8), 256, 0, stream>>>(AO, wob, wob, wob, d_out, d_out, d_out, 1);
}

// Round 2
// 147.098 us; speedup vs baseline: 1.8889x; 1.8889x over previous
//
#include <hip/hip_runtime.h>
#include <stdint.h>

typedef unsigned short u16;
typedef __attribute__((ext_vector_type(8))) short bf16x8;
typedef __attribute__((ext_vector_type(4))) short bf16x4;
typedef __attribute__((ext_vector_type(4))) float f32x4;
typedef __attribute__((ext_vector_type(4))) unsigned short u16x4;

#define S_ 2048
#define E_ 1024

__device__ __forceinline__ u16 f2bf(float f) {
  union { float f; unsigned u; } v; v.f = f;
  unsigned u = v.u;
  unsigned r = (u + 0x7FFFu + ((u >> 16) & 1u)) >> 16;
  return (u16)r;
}
__device__ __forceinline__ float bf2f(u16 h) {
  union { unsigned u; float f; } v; v.u = ((unsigned)h) << 16;
  return v.f;
}

typedef __attribute__((address_space(3))) void lds_void;
__device__ __forceinline__ unsigned lds_off(void* p) {
  return (unsigned)(unsigned long long)(lds_void*)p;
}
__device__ __forceinline__ void glds16(const u16* g, u16* l) {
  __builtin_amdgcn_global_load_lds(
      (const __attribute__((address_space(1))) void*)g,
      (__attribute__((address_space(3))) void*)l, 16, 0, 0);
}

// ---------------- cast f32 -> bf16 (x4 vectorized) ----------------
__global__ void k_cast(const float* __restrict__ in, u16* __restrict__ out, int n4) {
  int i = blockIdx.x * blockDim.x + threadIdx.x;
  if (i >= n4) return;
  float4 v = *((const float4*)in + i);
  u16x4 o;
  o.x = f2bf(v.x); o.y = f2bf(v.y); o.z = f2bf(v.z); o.w = f2bf(v.w);
  *((u16x4*)out + i) = o;
}

// ---------------- 128x128 tile bf16 GEMM (m97 structure: global_load_lds) ----------------
__global__ __launch_bounds__(256) void k_gemm(
    const u16* __restrict__ A,
    const u16* __restrict__ W0, const u16* __restrict__ W1, const u16* __restrict__ W2,
    void* O0, void* O1, void* O2, int outF32)
{
  __shared__ __align__(16) u16 As[128 * 32];
  __shared__ __align__(16) u16 Ws[128 * 32];
  int tid = threadIdx.x;
  int wid = tid >> 6, lane = tid & 63;
  int lg = lane >> 4, lr = lane & 15;
  int wsel = blockIdx.y >> 3, nb = blockIdx.y & 7;
  const u16* W = (wsel == 0) ? W0 : ((wsel == 1) ? W1 : W2);
  void* O = (wsel == 0) ? O0 : ((wsel == 1) ? O1 : O2);
  int m0 = blockIdx.x * 128;
  int n0 = nb * 128;
  int wr = wid >> 1, wc = wid & 1;

  f32x4 acc[4][4];
#pragma unroll
  for (int m = 0; m < 4; m++)
#pragma unroll
    for (int n = 0; n < 4; n++) acc[m][n] = (f32x4){0.f, 0.f, 0.f, 0.f};

  int srow = tid >> 2;
  int scol = (tid & 3) * 8;
  const u16* ag = A + (size_t)(m0 + srow) * 1024 + scol;
  const u16* wg = W + (size_t)(n0 + srow) * 1024 + scol;
  u16* asl = &As[tid * 8];
  u16* wsl = &Ws[tid * 8];

  for (int kt = 0; kt < 1024; kt += 32) {
    __syncthreads();
    glds16(ag + kt, asl);
    glds16(ag + kt + 64 * 1024, asl + 2048);
    glds16(wg + kt, wsl);
    glds16(wg + kt + 64 * 1024, wsl + 2048);
    __syncthreads();
    bf16x8 af[4], wf[4];
#pragma unroll
    for (int m = 0; m < 4; m++) af[m] = *(const bf16x8*)&As[(wr * 64 + m * 16 + lr) * 32 + lg * 8];
#pragma unroll
    for (int n = 0; n < 4; n++) wf[n] = *(const bf16x8*)&Ws[(wc * 64 + n * 16 + lr) * 32 + lg * 8];
#pragma unroll
    for (int m = 0; m < 4; m++)
#pragma unroll
      for (int n = 0; n < 4; n++)
        acc[m][n] = __builtin_amdgcn_mfma_f32_16x16x32_bf16(af[m], wf[n], acc[m][n], 0, 0, 0);
  }

#pragma unroll
  for (int m = 0; m < 4; m++) {
    int gr = m0 + wr * 64 + m * 16 + lg * 4;
#pragma unroll
    for (int n = 0; n < 4; n++) {
      int gc = n0 + wc * 64 + n * 16 + lr;
#pragma unroll
      for (int r = 0; r < 4; r++) {
        if (outF32) ((float*)O)[(size_t)(gr + r) * 1024 + gc] = acc[m][n][r];
        else ((u16*)O)[(size_t)(gr + r) * 1024 + gc] = f2bf(acc[m][n][r]);
      }
    }
  }
}

// ---------------- RoPE in place on Q and K ----------------
__global__ void k_rope(u16* __restrict__ Q, u16* __restrict__ K) {
  int idx = blockIdx.x * blockDim.x + threadIdx.x;
  int p = idx & 511;
  int srow = idx >> 9;
  int s = srow & (S_ - 1);
  int i = p & 31;
  float ang = (float)s * exp2f(-0.415241012f * (float)i);
  float sn, c;
  __sincosf(ang, &sn, &c);
  unsigned* qp = (unsigned*)Q + idx;
  unsigned qv = *qp;
  float e = bf2f((u16)(qv & 0xffff)), o = bf2f((u16)(qv >> 16));
  float re = e * c - o * sn, ro = e * sn + o * c;
  *qp = (unsigned)f2bf(re) | ((unsigned)f2bf(ro) << 16);
  unsigned* kp = (unsigned*)K + idx;
  unsigned kv = *kp;
  e = bf2f((u16)(kv & 0xffff)); o = bf2f((u16)(kv >> 16));
  re = e * c - o * sn; ro = e * sn + o * c;
  *kp = (unsigned)f2bf(re) | ((unsigned)f2bf(ro) << 16);
}

// ---------------- causal flash attention, KVBLK=64, LDS-staged K/V ----------------
// grid: x = bh (fast dim -> XCD locality), y = qb index (reversed: longest first)
// 4 waves/block, wave owns 16 q rows. Swapped QK^T: S^T = mfma(K, Q).
__global__ __launch_bounds__(256) void k_attn(
    const u16* __restrict__ Q, const u16* __restrict__ K,
    const u16* __restrict__ V, u16* __restrict__ AO)
{
  __shared__ __align__(16) u16 Ks[64 * 64];  // row-major [kv][d], XOR-swizzled
  __shared__ __align__(16) u16 Vs[64 * 64];  // subtiled [kv16][c][kv&15][d16]
  int tid = threadIdx.x;
  int wid = tid >> 6, lane = tid & 63;
  int lg = lane >> 4, lr = lane & 15;
  int bh = blockIdx.x;
  int qb = 31 - (int)blockIdx.y;
  int q0 = qb * 64 + wid * 16;
  size_t base = (size_t)(bh >> 4) * (2048u * 1024u) + (size_t)(bh & 15) * 64;

  const u16* qrow = Q + base + (size_t)(q0 + lr) * 1024 + lg * 8;
  bf16x8 qf0 = *(const bf16x8*)(qrow);
  bf16x8 qf1 = *(const bf16x8*)(qrow + 32);

  // staging: thread covers rows srow, srow+32; 16B chunk sch
  int srow = tid >> 3;
  int sch = tid & 7;
  const u16* kg = K + base + (size_t)srow * 1024 + sch * 8;
  const u16* vg = V + base + (size_t)srow * 1024 + sch * 8;
  int kwb0 = ((srow)*128 + sch * 16) ^ ((srow & 7) << 4);
  int kwb1 = ((srow + 32) * 128 + sch * 16) ^ ((srow & 7) << 4);
  int vwi0 = (srow >> 4) * 1024 + (sch >> 1) * 256 + (srow & 15) * 16 + (sch & 1) * 8;
  int vwi1 = ((srow + 32) >> 4) * 1024 + (sch >> 1) * 256 + (srow & 15) * 16 + (sch & 1) * 8;

  bf16x8 kr0 = *(const bf16x8*)(kg);
  bf16x8 kr1 = *(const bf16x8*)(kg + 32 * 1024);
  bf16x8 vr0 = *(const bf16x8*)(vg);
  bf16x8 vr1 = *(const bf16x8*)(vg + 32 * 1024);

  float m = -1e30f, lsum = 0.f;
  f32x4 o[4];
#pragma unroll
  for (int c = 0; c < 4; c++) o[c] = (f32x4){0.f, 0.f, 0.f, 0.f};

  int qg = q0 + lr;
  int ntile = qb + 1;
  unsigned vrd = lds_off(Vs) + (unsigned)(lane * 8);

  for (int t = 0; t < ntile; ++t) {
    __syncthreads();
    *(bf16x8*)((char*)Ks + kwb0) = kr0;
    *(bf16x8*)((char*)Ks + kwb1) = kr1;
    *(bf16x8*)(&Vs[vwi0]) = vr0;
    *(bf16x8*)(&Vs[vwi1]) = vr1;
    __syncthreads();
    if (t + 1 < ntile) {
      const u16* kg2 = kg + (size_t)(t + 1) * 64 * 1024;
      const u16* vg2 = vg + (size_t)(t + 1) * 64 * 1024;
      kr0 = *(const bf16x8*)(kg2);
      kr1 = *(const bf16x8*)(kg2 + 32 * 1024);
      vr0 = *(const bf16x8*)(vg2);
      vr1 = *(const bf16x8*)(vg2 + 32 * 1024);
    }
    // QK^T: 4 subtiles of 16 kv
    f32x4 sv[4];
    int kv0 = t * 64;
#pragma unroll
    for (int sub = 0; sub < 4; ++sub) {
      int row = sub * 16 + lr;
      int swz = (row & 7) << 4;
      bf16x8 kf0 = *(const bf16x8*)((const char*)Ks + ((row * 128 + lg * 16) ^ swz));
      bf16x8 kf1 = *(const bf16x8*)((const char*)Ks + ((row * 128 + 64 + lg * 16) ^ swz));
      f32x4 z = (f32x4){0.f, 0.f, 0.f, 0.f};
      z = __builtin_amdgcn_mfma_f32_16x16x32_bf16(kf0, qf0, z, 0, 0, 0);
      sv[sub] = __builtin_amdgcn_mfma_f32_16x16x32_bf16(kf1, qf1, z, 0, 0, 0);
    }
    // mask + scale
    if (t == ntile - 1) {
#pragma unroll
      for (int sub = 0; sub < 4; ++sub)
#pragma unroll
        for (int j = 0; j < 4; ++j) {
          int kvg = kv0 + sub * 16 + lg * 4 + j;
          sv[sub][j] = (kvg <= qg) ? sv[sub][j] * 0.125f : -1e30f;
        }
    } else {
#pragma unroll
      for (int sub = 0; sub < 4; ++sub)
#pragma unroll
        for (int j = 0; j < 4; ++j) sv[sub][j] *= 0.125f;
    }
    // online softmax over 64 kv
    float tm = -1e30f;
#pragma unroll
    for (int sub = 0; sub < 4; ++sub)
#pragma unroll
      for (int j = 0; j < 4; ++j) tm = fmaxf(tm, sv[sub][j]);
    tm = fmaxf(tm, __shfl_xor(tm, 16));
    tm = fmaxf(tm, __shfl_xor(tm, 32));
    float mn = fmaxf(m, tm);
    float corr = __expf(m - mn);
    m = mn;
    lsum *= corr;
#pragma unroll
    for (int c = 0; c < 4; ++c) {
      o[c][0] *= corr; o[c][1] *= corr; o[c][2] *= corr; o[c][3] *= corr;
    }
    bf16x4 pb[4];
#pragma unroll
    for (int sub = 0; sub < 4; ++sub)
#pragma unroll
      for (int j = 0; j < 4; ++j) {
        float p = __expf(sv[sub][j] - mn);
        lsum += p;
        pb[sub][j] = (short)f2bf(p);
      }
    // PV: per subtile, 4 tr-reads (one per 16-d chunk) + 4 MFMA
#pragma unroll
    for (int sub = 0; sub < 4; ++sub) {
      unsigned wa = vrd + (unsigned)(sub * 2048);
      bf16x4 va0, va1, va2, va3;
      asm volatile("ds_read_b64_tr_b16 %0, %1" : "=v"(va0) : "v"(wa));
      asm volatile("ds_read_b64_tr_b16 %0, %1 offset:512" : "=v"(va1) : "v"(wa));
      asm volatile("ds_read_b64_tr_b16 %0, %1 offset:1024" : "=v"(va2) : "v"(wa));
      asm volatile("ds_read_b64_tr_b16 %0, %1 offset:1536" : "=v"(va3) : "v"(wa));
      asm volatile("s_waitcnt lgkmcnt(0)" ::: "memory");
      __builtin_amdgcn_sched_barrier(0);
      o[0] = __builtin_amdgcn_mfma_f32_16x16x16bf16_1k(va0, pb[sub], o[0], 0, 0, 0);
      o[1] = __builtin_amdgcn_mfma_f32_16x16x16bf16_1k(va1, pb[sub], o[1], 0, 0, 0);
      o[2] = __builtin_amdgcn_mfma_f32_16x16x16bf16_1k(va2, pb[sub], o[2], 0, 0, 0);
      o[3] = __builtin_amdgcn_mfma_f32_16x16x16bf16_1k(va3, pb[sub], o[3], 0, 0, 0);
    }
  }

  float lt = lsum + __shfl_xor(lsum, 16);
  lt += __shfl_xor(lt, 32);
  float inv = 1.0f / lt;
  u16* orow = AO + base + (size_t)(q0 + lr) * 1024;
#pragma unroll
  for (int c = 0; c < 4; c++)
#pragma unroll
    for (int r = 0; r < 4; r++)
      orow[c * 16 + lg * 4 + r] = f2bf(o[c][r] * inv);
}

extern "C" void kernel_launch(void* const* d_in, const int* in_sizes, int n_in,
                              void* d_out, int out_size, void* d_ws, size_t ws_size,
                              hipStream_t stream) {
  const float* x = (const float*)d_in[0];
  const float* wq = (const float*)d_in[1];
  const float* wk = (const float*)d_in[2];
  const float* wv = (const float*)d_in[3];
  const float* wo = (const float*)d_in[4];

  char* ws = (char*)d_ws;
  u16* xb  = (u16*)(ws);
  u16* wqb = (u16*)(ws + 8388608);
  u16* wkb = (u16*)(ws + 10485760);
  u16* wvb = (u16*)(ws + 12582912);
  u16* wob = (u16*)(ws + 14680064);
  u16* Qb  = (u16*)(ws + 16777216);
  u16* Kb  = (u16*)(ws + 25165824);
  u16* Vb  = (u16*)(ws + 33554432);
  u16* AO  = (u16*)(ws + 41943040);

  k_cast<<<4096, 256, 0, stream>>>(x, xb, 1048576);
  k_cast<<<1024, 256, 0, stream>>>(wq, wqb, 262144);
  k_cast<<<1024, 256, 0, stream>>>(wk, wkb, 262144);
  k_cast<<<1024, 256, 0, stream>>>(wv, wvb, 262144);
  k_cast<<<1024, 256, 0, stream>>>(wo, wob, 262144);

  k_gemm<<<dim3(32, 24), 256, 0, stream>>>(xb, wqb, wkb, wvb, Qb, Kb, Vb, 0);
  k_rope<<<8192, 256, 0, stream>>>(Qb, Kb);
  k_attn<<<dim3(32, 32), 256, 0, stream>>>(Qb, Kb, Vb, AO);
  k_gemm<<<dim3(32, 8), 256, 0, stream>>>(AO, wob, wob, wob, d_out, d_out, d_out, 1);
}

// Round 3
// 119.969 us; speedup vs baseline: 2.3160x; 1.2261x over previous
//
#include <hip/hip_runtime.h>
#include <stdint.h>

typedef unsigned short u16;
typedef __attribute__((ext_vector_type(8))) short bf16x8;
typedef __attribute__((ext_vector_type(4))) short bf16x4;
typedef __attribute__((ext_vector_type(4))) float f32x4;
typedef __attribute__((ext_vector_type(4))) unsigned short u16x4;

#define S_ 2048
#define E_ 1024

__device__ __forceinline__ u16 f2bf(float f) {
  union { float f; unsigned u; } v; v.f = f;
  unsigned u = v.u;
  unsigned r = (u + 0x7FFFu + ((u >> 16) & 1u)) >> 16;
  return (u16)r;
}
__device__ __forceinline__ float bf2f(u16 h) {
  union { unsigned u; float f; } v; v.u = ((unsigned)h) << 16;
  return v.f;
}

typedef __attribute__((address_space(3))) void lds_void;
__device__ __forceinline__ unsigned lds_off(void* p) {
  return (unsigned)(unsigned long long)(lds_void*)p;
}
__device__ __forceinline__ void glds16(const u16* g, u16* l) {
  __builtin_amdgcn_global_load_lds(
      (const __attribute__((address_space(1))) void*)g,
      (__attribute__((address_space(3))) void*)l, 16, 0, 0);
}

// ---------------- fused cast f32 -> bf16 for all 5 inputs ----------------
__global__ void k_cast5(const float* __restrict__ x,
                        const float* __restrict__ wq, const float* __restrict__ wk,
                        const float* __restrict__ wv, const float* __restrict__ wo,
                        u16* __restrict__ xb, u16* __restrict__ wqb, u16* __restrict__ wkb,
                        u16* __restrict__ wvb, u16* __restrict__ wob) {
  int i = blockIdx.x * blockDim.x + threadIdx.x;  // < 2097152 float4s
  const float* src; u16* dst; int off;
  if (i < 1048576) { src = x; dst = xb; off = i; }
  else {
    int j = i - 1048576;
    int w = j >> 18; off = j & 262143;
    src = (w == 0) ? wq : (w == 1) ? wk : (w == 2) ? wv : wo;
    dst = (w == 0) ? wqb : (w == 1) ? wkb : (w == 2) ? wvb : wob;
  }
  float4 v = *((const float4*)src + off);
  u16x4 o;
  o.x = f2bf(v.x); o.y = f2bf(v.y); o.z = f2bf(v.z); o.w = f2bf(v.w);
  *((u16x4*)dst + off) = o;
}

// ---------------- 128x128 tile bf16 GEMM, 2-phase double-buffered LDS ----------------
// T3-minimum recipe: STAGE(next) -> ds_read(cur)+MFMA -> one barrier per K-step.
// LDS read swizzle: chunk ^= (row>>1)&3, matched by pre-swizzled global source.
__global__ __launch_bounds__(256) void k_gemm(
    const u16* __restrict__ A,
    const u16* __restrict__ W0, const u16* __restrict__ W1, const u16* __restrict__ W2,
    void* O0, void* O1, void* O2, int outF32)
{
  __shared__ __align__(16) u16 As[2][128 * 32];
  __shared__ __align__(16) u16 Ws[2][128 * 32];
  int tid = threadIdx.x;
  int wid = tid >> 6, lane = tid & 63;
  int lg = lane >> 4, lr = lane & 15;
  int wsel = blockIdx.y >> 3, nb = blockIdx.y & 7;
  const u16* W = (wsel == 0) ? W0 : ((wsel == 1) ? W1 : W2);
  void* O = (wsel == 0) ? O0 : ((wsel == 1) ? O1 : O2);
  int m0 = blockIdx.x * 128;
  int n0 = nb * 128;
  int wr = wid >> 1, wc = wid & 1;

  f32x4 acc[4][4];
#pragma unroll
  for (int m = 0; m < 4; m++)
#pragma unroll
    for (int n = 0; n < 4; n++) acc[m][n] = (f32x4){0.f, 0.f, 0.f, 0.f};

  int srow = tid >> 2;
  int schunk = (tid & 3) ^ ((tid >> 3) & 3);  // pre-swizzled source chunk (involution)
  const u16* ag = A + (size_t)(m0 + srow) * 1024 + schunk * 8;
  const u16* wg = W + (size_t)(n0 + srow) * 1024 + schunk * 8;

  int buf = 0;
  // prologue: stage K-tile 0
  glds16(ag, &As[0][tid * 8]);
  glds16(ag + 65536, &As[0][tid * 8 + 2048]);
  glds16(wg, &Ws[0][tid * 8]);
  glds16(wg + 65536, &Ws[0][tid * 8 + 2048]);
  __syncthreads();

  for (int kt = 0; kt < 1024; kt += 32) {
    if (kt + 32 < 1024) {  // stage next tile into other buffer
      glds16(ag + kt + 32, &As[buf ^ 1][tid * 8]);
      glds16(ag + kt + 32 + 65536, &As[buf ^ 1][tid * 8 + 2048]);
      glds16(wg + kt + 32, &Ws[buf ^ 1][tid * 8]);
      glds16(wg + kt + 32 + 65536, &Ws[buf ^ 1][tid * 8 + 2048]);
    }
    bf16x8 af[4], wf[4];
#pragma unroll
    for (int m = 0; m < 4; m++) {
      int row = wr * 64 + m * 16 + lr;
      af[m] = *(const bf16x8*)&As[buf][row * 32 + ((lg ^ ((row >> 1) & 3)) * 8)];
    }
#pragma unroll
    for (int n = 0; n < 4; n++) {
      int row = wc * 64 + n * 16 + lr;
      wf[n] = *(const bf16x8*)&Ws[buf][row * 32 + ((lg ^ ((row >> 1) & 3)) * 8)];
    }
    __builtin_amdgcn_s_setprio(1);
#pragma unroll
    for (int m = 0; m < 4; m++)
#pragma unroll
      for (int n = 0; n < 4; n++)
        acc[m][n] = __builtin_amdgcn_mfma_f32_16x16x32_bf16(af[m], wf[n], acc[m][n], 0, 0, 0);
    __builtin_amdgcn_s_setprio(0);
    __syncthreads();  // drains vmcnt(0): next tile landed; all waves done with buf
    buf ^= 1;
  }

#pragma unroll
  for (int m = 0; m < 4; m++) {
    int gr = m0 + wr * 64 + m * 16 + lg * 4;
#pragma unroll
    for (int n = 0; n < 4; n++) {
      int gc = n0 + wc * 64 + n * 16 + lr;
#pragma unroll
      for (int r = 0; r < 4; r++) {
        if (outF32) ((float*)O)[(size_t)(gr + r) * 1024 + gc] = acc[m][n][r];
        else ((u16*)O)[(size_t)(gr + r) * 1024 + gc] = f2bf(acc[m][n][r]);
      }
    }
  }
}

// ---------------- RoPE in place on Q and K ----------------
__global__ void k_rope(u16* __restrict__ Q, u16* __restrict__ K) {
  int idx = blockIdx.x * blockDim.x + threadIdx.x;
  int p = idx & 511;
  int srow = idx >> 9;
  int s = srow & (S_ - 1);
  int i = p & 31;
  float ang = (float)s * exp2f(-0.415241012f * (float)i);
  float sn, c;
  __sincosf(ang, &sn, &c);
  unsigned* qp = (unsigned*)Q + idx;
  unsigned qv = *qp;
  float e = bf2f((u16)(qv & 0xffff)), o = bf2f((u16)(qv >> 16));
  float re = e * c - o * sn, ro = e * sn + o * c;
  *qp = (unsigned)f2bf(re) | ((unsigned)f2bf(ro) << 16);
  unsigned* kp = (unsigned*)K + idx;
  unsigned kv = *kp;
  e = bf2f((u16)(kv & 0xffff)); o = bf2f((u16)(kv >> 16));
  re = e * c - o * sn; ro = e * sn + o * c;
  *kp = (unsigned)f2bf(re) | ((unsigned)f2bf(ro) << 16);
}

// ---------------- causal flash attention, KVBLK=64, LDS-staged K/V ----------------
__global__ __launch_bounds__(256) void k_attn(
    const u16* __restrict__ Q, const u16* __restrict__ K,
    const u16* __restrict__ V, u16* __restrict__ AO)
{
  __shared__ __align__(16) u16 Ks[64 * 64];
  __shared__ __align__(16) u16 Vs[64 * 64];
  int tid = threadIdx.x;
  int wid = tid >> 6, lane = tid & 63;
  int lg = lane >> 4, lr = lane & 15;
  int bh = blockIdx.x;
  int qb = 31 - (int)blockIdx.y;
  int q0 = qb * 64 + wid * 16;
  size_t base = (size_t)(bh >> 4) * (2048u * 1024u) + (size_t)(bh & 15) * 64;

  const u16* qrow = Q + base + (size_t)(q0 + lr) * 1024 + lg * 8;
  bf16x8 qf0 = *(const bf16x8*)(qrow);
  bf16x8 qf1 = *(const bf16x8*)(qrow + 32);

  int srow = tid >> 3;
  int sch = tid & 7;
  const u16* kg = K + base + (size_t)srow * 1024 + sch * 8;
  const u16* vg = V + base + (size_t)srow * 1024 + sch * 8;
  int kwb0 = ((srow)*128 + sch * 16) ^ ((srow & 7) << 4);
  int kwb1 = ((srow + 32) * 128 + sch * 16) ^ ((srow & 7) << 4);
  int vwi0 = (srow >> 4) * 1024 + (sch >> 1) * 256 + (srow & 15) * 16 + (sch & 1) * 8;
  int vwi1 = ((srow + 32) >> 4) * 1024 + (sch >> 1) * 256 + (srow & 15) * 16 + (sch & 1) * 8;

  bf16x8 kr0 = *(const bf16x8*)(kg);
  bf16x8 kr1 = *(const bf16x8*)(kg + 32 * 1024);
  bf16x8 vr0 = *(const bf16x8*)(vg);
  bf16x8 vr1 = *(const bf16x8*)(vg + 32 * 1024);

  float m = -1e30f, lsum = 0.f;
  f32x4 o[4];
#pragma unroll
  for (int c = 0; c < 4; c++) o[c] = (f32x4){0.f, 0.f, 0.f, 0.f};

  int qg = q0 + lr;
  int ntile = qb + 1;
  unsigned vrd = lds_off(Vs) + (unsigned)(lane * 8);

  for (int t = 0; t < ntile; ++t) {
    __syncthreads();
    *(bf16x8*)((char*)Ks + kwb0) = kr0;
    *(bf16x8*)((char*)Ks + kwb1) = kr1;
    *(bf16x8*)(&Vs[vwi0]) = vr0;
    *(bf16x8*)(&Vs[vwi1]) = vr1;
    __syncthreads();
    if (t + 1 < ntile) {
      const u16* kg2 = kg + (size_t)(t + 1) * 64 * 1024;
      const u16* vg2 = vg + (size_t)(t + 1) * 64 * 1024;
      kr0 = *(const bf16x8*)(kg2);
      kr1 = *(const bf16x8*)(kg2 + 32 * 1024);
      vr0 = *(const bf16x8*)(vg2);
      vr1 = *(const bf16x8*)(vg2 + 32 * 1024);
    }
    f32x4 sv[4];
    int kv0 = t * 64;
    __builtin_amdgcn_s_setprio(1);
#pragma unroll
    for (int sub = 0; sub < 4; ++sub) {
      int row = sub * 16 + lr;
      int swz = (row & 7) << 4;
      bf16x8 kf0 = *(const bf16x8*)((const char*)Ks + ((row * 128 + lg * 16) ^ swz));
      bf16x8 kf1 = *(const bf16x8*)((const char*)Ks + ((row * 128 + 64 + lg * 16) ^ swz));
      f32x4 z = (f32x4){0.f, 0.f, 0.f, 0.f};
      z = __builtin_amdgcn_mfma_f32_16x16x32_bf16(kf0, qf0, z, 0, 0, 0);
      sv[sub] = __builtin_amdgcn_mfma_f32_16x16x32_bf16(kf1, qf1, z, 0, 0, 0);
    }
    __builtin_amdgcn_s_setprio(0);
    if (t == ntile - 1) {
#pragma unroll
      for (int sub = 0; sub < 4; ++sub)
#pragma unroll
        for (int j = 0; j < 4; ++j) {
          int kvg = kv0 + sub * 16 + lg * 4 + j;
          sv[sub][j] = (kvg <= qg) ? sv[sub][j] * 0.125f : -1e30f;
        }
    } else {
#pragma unroll
      for (int sub = 0; sub < 4; ++sub)
#pragma unroll
        for (int j = 0; j < 4; ++j) sv[sub][j] *= 0.125f;
    }
    float tm = -1e30f;
#pragma unroll
    for (int sub = 0; sub < 4; ++sub)
#pragma unroll
      for (int j = 0; j < 4; ++j) tm = fmaxf(tm, sv[sub][j]);
    tm = fmaxf(tm, __shfl_xor(tm, 16));
    tm = fmaxf(tm, __shfl_xor(tm, 32));
    float mn = fmaxf(m, tm);
    float corr = __expf(m - mn);
    m = mn;
    lsum *= corr;
#pragma unroll
    for (int c = 0; c < 4; ++c) {
      o[c][0] *= corr; o[c][1] *= corr; o[c][2] *= corr; o[c][3] *= corr;
    }
    bf16x4 pb[4];
#pragma unroll
    for (int sub = 0; sub < 4; ++sub)
#pragma unroll
      for (int j = 0; j < 4; ++j) {
        float p = __expf(sv[sub][j] - mn);
        lsum += p;
        pb[sub][j] = (short)f2bf(p);
      }
#pragma unroll
    for (int sub = 0; sub < 4; ++sub) {
      unsigned wa = vrd + (unsigned)(sub * 2048);
      bf16x4 va0, va1, va2, va3;
      asm volatile("ds_read_b64_tr_b16 %0, %1" : "=v"(va0) : "v"(wa));
      asm volatile("ds_read_b64_tr_b16 %0, %1 offset:512" : "=v"(va1) : "v"(wa));
      asm volatile("ds_read_b64_tr_b16 %0, %1 offset:1024" : "=v"(va2) : "v"(wa));
      asm volatile("ds_read_b64_tr_b16 %0, %1 offset:1536" : "=v"(va3) : "v"(wa));
      asm volatile("s_waitcnt lgkmcnt(0)" ::: "memory");
      __builtin_amdgcn_sched_barrier(0);
      __builtin_amdgcn_s_setprio(1);
      o[0] = __builtin_amdgcn_mfma_f32_16x16x16bf16_1k(va0, pb[sub], o[0], 0, 0, 0);
      o[1] = __builtin_amdgcn_mfma_f32_16x16x16bf16_1k(va1, pb[sub], o[1], 0, 0, 0);
      o[2] = __builtin_amdgcn_mfma_f32_16x16x16bf16_1k(va2, pb[sub], o[2], 0, 0, 0);
      o[3] = __builtin_amdgcn_mfma_f32_16x16x16bf16_1k(va3, pb[sub], o[3], 0, 0, 0);
      __builtin_amdgcn_s_setprio(0);
    }
  }

  float lt = lsum + __shfl_xor(lsum, 16);
  lt += __shfl_xor(lt, 32);
  float inv = 1.0f / lt;
  u16* orow = AO + base + (size_t)(q0 + lr) * 1024;
#pragma unroll
  for (int c = 0; c < 4; c++)
#pragma unroll
    for (int r = 0; r < 4; r++)
      orow[c * 16 + lg * 4 + r] = f2bf(o[c][r] * inv);
}

extern "C" void kernel_launch(void* const* d_in, const int* in_sizes, int n_in,
                              void* d_out, int out_size, void* d_ws, size_t ws_size,
                              hipStream_t stream) {
  const float* x = (const float*)d_in[0];
  const float* wq = (const float*)d_in[1];
  const float* wk = (const float*)d_in[2];
  const float* wv = (const float*)d_in[3];
  const float* wo = (const float*)d_in[4];

  char* ws = (char*)d_ws;
  u16* xb  = (u16*)(ws);
  u16* wqb = (u16*)(ws + 8388608);
  u16* wkb = (u16*)(ws + 10485760);
  u16* wvb = (u16*)(ws + 12582912);
  u16* wob = (u16*)(ws + 14680064);
  u16* Qb  = (u16*)(ws + 16777216);
  u16* Kb  = (u16*)(ws + 25165824);
  u16* Vb  = (u16*)(ws + 33554432);
  u16* AO  = (u16*)(ws + 41943040);

  k_cast5<<<8192, 256, 0, stream>>>(x, wq, wk, wv, wo, xb, wqb, wkb, wvb, wob);
  k_gemm<<<dim3(32, 24), 256, 0, stream>>>(xb, wqb, wkb, wvb, Qb, Kb, Vb, 0);
  k_rope<<<8192, 256, 0, stream>>>(Qb, Kb);
  k_attn<<<dim3(32, 32), 256, 0, stream>>>(Qb, Kb, Vb, AO);
  k_gemm<<<dim3(32, 8), 256, 0, stream>>>(AO, wob, wob, wob, d_out, d_out, d_out, 1);
}

// Round 4
// 115.726 us; speedup vs baseline: 2.4009x; 1.0367x over previous
//
#include <hip/hip_runtime.h>
#include <stdint.h>

typedef unsigned short u16;
typedef __attribute__((ext_vector_type(8))) short bf16x8;
typedef __attribute__((ext_vector_type(4))) short bf16x4;
typedef __attribute__((ext_vector_type(4))) float f32x4;
typedef __attribute__((ext_vector_type(4))) unsigned short u16x4;
typedef __attribute__((ext_vector_type(2))) unsigned u32x2;

#define S_ 2048
#define E_ 1024
// 0.125 (1/sqrt(64)) * log2(e): folds softmax scale + exp->exp2 into Q
#define QSCALE 0.18033688011112042f

__device__ __forceinline__ u16 f2bf(float f) {
  union { float f; unsigned u; } v; v.f = f;
  unsigned u = v.u;
  unsigned r = (u + 0x7FFFu + ((u >> 16) & 1u)) >> 16;
  return (u16)r;
}
__device__ __forceinline__ float bf2f(u16 h) {
  union { unsigned u; float f; } v; v.u = ((unsigned)h) << 16;
  return v.f;
}
__device__ __forceinline__ unsigned cvtpk(float a, float b) {
  unsigned r;
  asm("v_cvt_pk_bf16_f32 %0, %1, %2" : "=v"(r) : "v"(a), "v"(b));
  return r;
}
__device__ __forceinline__ bf16x4 pk4(float a, float b, float c, float d) {
  union { u32x2 u; bf16x4 v; } U;
  U.u[0] = cvtpk(a, b);
  U.u[1] = cvtpk(c, d);
  return U.v;
}

typedef __attribute__((address_space(3))) void lds_void;
__device__ __forceinline__ unsigned lds_off(void* p) {
  return (unsigned)(unsigned long long)(lds_void*)p;
}
__device__ __forceinline__ void glds16(const u16* g, u16* l) {
  __builtin_amdgcn_global_load_lds(
      (const __attribute__((address_space(1))) void*)g,
      (__attribute__((address_space(3))) void*)l, 16, 0, 0);
}

// ---------------- fused cast f32 -> bf16 for all 5 inputs ----------------
__global__ void k_cast5(const float* __restrict__ x,
                        const float* __restrict__ wq, const float* __restrict__ wk,
                        const float* __restrict__ wv, const float* __restrict__ wo,
                        u16* __restrict__ xb, u16* __restrict__ wqb, u16* __restrict__ wkb,
                        u16* __restrict__ wvb, u16* __restrict__ wob) {
  int i = blockIdx.x * blockDim.x + threadIdx.x;
  const float* src; u16* dst; int off;
  if (i < 1048576) { src = x; dst = xb; off = i; }
  else {
    int j = i - 1048576;
    int w = j >> 18; off = j & 262143;
    src = (w == 0) ? wq : (w == 1) ? wk : (w == 2) ? wv : wo;
    dst = (w == 0) ? wqb : (w == 1) ? wkb : (w == 2) ? wvb : wob;
  }
  float4 v = *((const float4*)src + off);
  u16x4 o;
  o.x = f2bf(v.x); o.y = f2bf(v.y); o.z = f2bf(v.z); o.w = f2bf(v.w);
  *((u16x4*)dst + off) = o;
}

// ---------------- 128x128 tile bf16 GEMM, 2-phase double-buffered LDS ----------------
__global__ __launch_bounds__(256) void k_gemm(
    const u16* __restrict__ A,
    const u16* __restrict__ W0, const u16* __restrict__ W1, const u16* __restrict__ W2,
    void* O0, void* O1, void* O2, int outF32)
{
  __shared__ __align__(16) u16 As[2][128 * 32];
  __shared__ __align__(16) u16 Ws[2][128 * 32];
  int tid = threadIdx.x;
  int wid = tid >> 6, lane = tid & 63;
  int lg = lane >> 4, lr = lane & 15;
  int wsel = blockIdx.y >> 3, nb = blockIdx.y & 7;
  const u16* W = (wsel == 0) ? W0 : ((wsel == 1) ? W1 : W2);
  void* O = (wsel == 0) ? O0 : ((wsel == 1) ? O1 : O2);
  int m0 = blockIdx.x * 128;
  int n0 = nb * 128;
  int wr = wid >> 1, wc = wid & 1;

  f32x4 acc[4][4];
#pragma unroll
  for (int m = 0; m < 4; m++)
#pragma unroll
    for (int n = 0; n < 4; n++) acc[m][n] = (f32x4){0.f, 0.f, 0.f, 0.f};

  int srow = tid >> 2;
  int schunk = (tid & 3) ^ ((tid >> 3) & 3);
  const u16* ag = A + (size_t)(m0 + srow) * 1024 + schunk * 8;
  const u16* wg = W + (size_t)(n0 + srow) * 1024 + schunk * 8;

  int buf = 0;
  glds16(ag, &As[0][tid * 8]);
  glds16(ag + 65536, &As[0][tid * 8 + 2048]);
  glds16(wg, &Ws[0][tid * 8]);
  glds16(wg + 65536, &Ws[0][tid * 8 + 2048]);
  __syncthreads();

  for (int kt = 0; kt < 1024; kt += 32) {
    if (kt + 32 < 1024) {
      glds16(ag + kt + 32, &As[buf ^ 1][tid * 8]);
      glds16(ag + kt + 32 + 65536, &As[buf ^ 1][tid * 8 + 2048]);
      glds16(wg + kt + 32, &Ws[buf ^ 1][tid * 8]);
      glds16(wg + kt + 32 + 65536, &Ws[buf ^ 1][tid * 8 + 2048]);
    }
    bf16x8 af[4], wf[4];
#pragma unroll
    for (int m = 0; m < 4; m++) {
      int row = wr * 64 + m * 16 + lr;
      af[m] = *(const bf16x8*)&As[buf][row * 32 + ((lg ^ ((row >> 1) & 3)) * 8)];
    }
#pragma unroll
    for (int n = 0; n < 4; n++) {
      int row = wc * 64 + n * 16 + lr;
      wf[n] = *(const bf16x8*)&Ws[buf][row * 32 + ((lg ^ ((row >> 1) & 3)) * 8)];
    }
    __builtin_amdgcn_s_setprio(1);
#pragma unroll
    for (int m = 0; m < 4; m++)
#pragma unroll
      for (int n = 0; n < 4; n++)
        acc[m][n] = __builtin_amdgcn_mfma_f32_16x16x32_bf16(af[m], wf[n], acc[m][n], 0, 0, 0);
    __builtin_amdgcn_s_setprio(0);
    __syncthreads();
    buf ^= 1;
  }

#pragma unroll
  for (int m = 0; m < 4; m++) {
    int gr = m0 + wr * 64 + m * 16 + lg * 4;
#pragma unroll
    for (int n = 0; n < 4; n++) {
      int gc = n0 + wc * 64 + n * 16 + lr;
#pragma unroll
      for (int r = 0; r < 4; r++) {
        if (outF32) ((float*)O)[(size_t)(gr + r) * 1024 + gc] = acc[m][n][r];
        else ((u16*)O)[(size_t)(gr + r) * 1024 + gc] = f2bf(acc[m][n][r]);
      }
    }
  }
}

// ---------------- RoPE in place; Q additionally scaled by QSCALE ----------------
__global__ void k_rope(u16* __restrict__ Q, u16* __restrict__ K) {
  int idx = blockIdx.x * blockDim.x + threadIdx.x;
  int p = idx & 511;
  int srow = idx >> 9;
  int s = srow & (S_ - 1);
  int i = p & 31;
  float ang = (float)s * exp2f(-0.415241012f * (float)i);
  float sn, c;
  __sincosf(ang, &sn, &c);
  unsigned* qp = (unsigned*)Q + idx;
  unsigned qv = *qp;
  float e = bf2f((u16)(qv & 0xffff)), o = bf2f((u16)(qv >> 16));
  float re = (e * c - o * sn) * QSCALE, ro = (e * sn + o * c) * QSCALE;
  *qp = cvtpk(re, ro);
  unsigned* kp = (unsigned*)K + idx;
  unsigned kv = *kp;
  e = bf2f((u16)(kv & 0xffff)); o = bf2f((u16)(kv >> 16));
  re = e * c - o * sn; ro = e * sn + o * c;
  *kp = cvtpk(re, ro);
}

// ---------------- causal flash attention, KVBLK=64, exp2-domain softmax ----------------
__global__ __launch_bounds__(256) void k_attn(
    const u16* __restrict__ Q, const u16* __restrict__ K,
    const u16* __restrict__ V, u16* __restrict__ AO)
{
  __shared__ __align__(16) u16 Ks[64 * 64];
  __shared__ __align__(16) u16 Vs[64 * 64];
  int tid = threadIdx.x;
  int wid = tid >> 6, lane = tid & 63;
  int lg = lane >> 4, lr = lane & 15;
  int bh = blockIdx.x;
  int qb = 31 - (int)blockIdx.y;
  int q0 = qb * 64 + wid * 16;
  size_t base = (size_t)(bh >> 4) * (2048u * 1024u) + (size_t)(bh & 15) * 64;

  const u16* qrow = Q + base + (size_t)(q0 + lr) * 1024 + lg * 8;
  bf16x8 qf0 = *(const bf16x8*)(qrow);
  bf16x8 qf1 = *(const bf16x8*)(qrow + 32);

  int srow = tid >> 3;
  int sch = tid & 7;
  const u16* kg = K + base + (size_t)srow * 1024 + sch * 8;
  const u16* vg = V + base + (size_t)srow * 1024 + sch * 8;
  int kwb0 = ((srow)*128 + sch * 16) ^ ((srow & 7) << 4);
  int kwb1 = ((srow + 32) * 128 + sch * 16) ^ ((srow & 7) << 4);
  int vwi0 = (srow >> 4) * 1024 + (sch >> 1) * 256 + (srow & 15) * 16 + (sch & 1) * 8;
  int vwi1 = ((srow + 32) >> 4) * 1024 + (sch >> 1) * 256 + (srow & 15) * 16 + (sch & 1) * 8;

  bf16x8 kr0 = *(const bf16x8*)(kg);
  bf16x8 kr1 = *(const bf16x8*)(kg + 32 * 1024);
  bf16x8 vr0 = *(const bf16x8*)(vg);
  bf16x8 vr1 = *(const bf16x8*)(vg + 32 * 1024);
  const u16* kgp = kg + 64 * 1024;
  const u16* vgp = vg + 64 * 1024;

  float m = -1e30f, lsum = 0.f;
  f32x4 o[4];
#pragma unroll
  for (int c = 0; c < 4; c++) o[c] = (f32x4){0.f, 0.f, 0.f, 0.f};

  int qg = q0 + lr;
  int ntile = qb + 1;
  unsigned vrd = lds_off(Vs) + (unsigned)(lane * 8);

  for (int t = 0; t < ntile; ++t) {
    __syncthreads();
    *(bf16x8*)((char*)Ks + kwb0) = kr0;
    *(bf16x8*)((char*)Ks + kwb1) = kr1;
    *(bf16x8*)(&Vs[vwi0]) = vr0;
    *(bf16x8*)(&Vs[vwi1]) = vr1;
    __syncthreads();
    if (t + 1 < ntile) {
      kr0 = *(const bf16x8*)(kgp);
      kr1 = *(const bf16x8*)(kgp + 32 * 1024);
      vr0 = *(const bf16x8*)(vgp);
      vr1 = *(const bf16x8*)(vgp + 32 * 1024);
      kgp += 64 * 1024;
      vgp += 64 * 1024;
    }
    f32x4 sv[4];
    int kv0 = t * 64;
    __builtin_amdgcn_s_setprio(1);
#pragma unroll
    for (int sub = 0; sub < 4; ++sub) {
      int row = sub * 16 + lr;
      int swz = (row & 7) << 4;
      bf16x8 kf0 = *(const bf16x8*)((const char*)Ks + ((row * 128 + lg * 16) ^ swz));
      bf16x8 kf1 = *(const bf16x8*)((const char*)Ks + ((row * 128 + 64 + lg * 16) ^ swz));
      f32x4 z = (f32x4){0.f, 0.f, 0.f, 0.f};
      z = __builtin_amdgcn_mfma_f32_16x16x32_bf16(kf0, qf0, z, 0, 0, 0);
      sv[sub] = __builtin_amdgcn_mfma_f32_16x16x32_bf16(kf1, qf1, z, 0, 0, 0);
    }
    __builtin_amdgcn_s_setprio(0);
    if (t == ntile - 1) {
#pragma unroll
      for (int sub = 0; sub < 4; ++sub)
#pragma unroll
        for (int j = 0; j < 4; ++j) {
          int kvg = kv0 + sub * 16 + lg * 4 + j;
          sv[sub][j] = (kvg <= qg) ? sv[sub][j] : -1e30f;
        }
    }
    // tile max (per q row)
    float tm = fmaxf(fmaxf(fmaxf(sv[0][0], sv[0][1]), fmaxf(sv[0][2], sv[0][3])),
                     fmaxf(fmaxf(sv[1][0], sv[1][1]), fmaxf(sv[1][2], sv[1][3])));
    tm = fmaxf(tm, fmaxf(fmaxf(fmaxf(sv[2][0], sv[2][1]), fmaxf(sv[2][2], sv[2][3])),
                         fmaxf(fmaxf(sv[3][0], sv[3][1]), fmaxf(sv[3][2], sv[3][3]))));
    tm = fmaxf(tm, __shfl_xor(tm, 16));
    tm = fmaxf(tm, __shfl_xor(tm, 32));
    // defer-max: rescale only when tile max exceeds running max by > 8
    if (!__all(tm <= m + 8.f)) {
      float mn = fmaxf(m, tm);
      float corr = __builtin_amdgcn_exp2f(m - mn);
      m = mn;
      lsum *= corr;
#pragma unroll
      for (int c = 0; c < 4; ++c) {
        o[c][0] *= corr; o[c][1] *= corr; o[c][2] *= corr; o[c][3] *= corr;
      }
    }
    bf16x4 pb[4];
#pragma unroll
    for (int sub = 0; sub < 4; ++sub) {
      float p0 = __builtin_amdgcn_exp2f(sv[sub][0] - m);
      float p1 = __builtin_amdgcn_exp2f(sv[sub][1] - m);
      float p2 = __builtin_amdgcn_exp2f(sv[sub][2] - m);
      float p3 = __builtin_amdgcn_exp2f(sv[sub][3] - m);
      lsum += (p0 + p1) + (p2 + p3);
      pb[sub] = pk4(p0, p1, p2, p3);
    }
#pragma unroll
    for (int sub = 0; sub < 4; ++sub) {
      unsigned wa = vrd + (unsigned)(sub * 2048);
      bf16x4 va0, va1, va2, va3;
      asm volatile("ds_read_b64_tr_b16 %0, %1" : "=v"(va0) : "v"(wa));
      asm volatile("ds_read_b64_tr_b16 %0, %1 offset:512" : "=v"(va1) : "v"(wa));
      asm volatile("ds_read_b64_tr_b16 %0, %1 offset:1024" : "=v"(va2) : "v"(wa));
      asm volatile("ds_read_b64_tr_b16 %0, %1 offset:1536" : "=v"(va3) : "v"(wa));
      asm volatile("s_waitcnt lgkmcnt(0)" ::: "memory");
      __builtin_amdgcn_sched_barrier(0);
      __builtin_amdgcn_s_setprio(1);
      o[0] = __builtin_amdgcn_mfma_f32_16x16x16bf16_1k(va0, pb[sub], o[0], 0, 0, 0);
      o[1] = __builtin_amdgcn_mfma_f32_16x16x16bf16_1k(va1, pb[sub], o[1], 0, 0, 0);
      o[2] = __builtin_amdgcn_mfma_f32_16x16x16bf16_1k(va2, pb[sub], o[2], 0, 0, 0);
      o[3] = __builtin_amdgcn_mfma_f32_16x16x16bf16_1k(va3, pb[sub], o[3], 0, 0, 0);
      __builtin_amdgcn_s_setprio(0);
    }
  }

  float lt = lsum + __shfl_xor(lsum, 16);
  lt += __shfl_xor(lt, 32);
  float inv = 1.0f / lt;
  u16* orow = AO + base + (size_t)(q0 + lr) * 1024;
#pragma unroll
  for (int c = 0; c < 4; c++) {
    u32x2 pk;
    pk[0] = cvtpk(o[c][0] * inv, o[c][1] * inv);
    pk[1] = cvtpk(o[c][2] * inv, o[c][3] * inv);
    *(u32x2*)&orow[c * 16 + lg * 4] = pk;
  }
}

extern "C" void kernel_launch(void* const* d_in, const int* in_sizes, int n_in,
                              void* d_out, int out_size, void* d_ws, size_t ws_size,
                              hipStream_t stream) {
  const float* x = (const float*)d_in[0];
  const float* wq = (const float*)d_in[1];
  const float* wk = (const float*)d_in[2];
  const float* wv = (const float*)d_in[3];
  const float* wo = (const float*)d_in[4];

  char* ws = (char*)d_ws;
  u16* xb  = (u16*)(ws);
  u16* wqb = (u16*)(ws + 8388608);
  u16* wkb = (u16*)(ws + 10485760);
  u16* wvb = (u16*)(ws + 12582912);
  u16* wob = (u16*)(ws + 14680064);
  u16* Qb  = (u16*)(ws + 16777216);
  u16* Kb  = (u16*)(ws + 25165824);
  u16* Vb  = (u16*)(ws + 33554432);
  u16* AO  = (u16*)(ws + 41943040);

  k_cast5<<<8192, 256, 0, stream>>>(x, wq, wk, wv, wo, xb, wqb, wkb, wvb, wob);
  k_gemm<<<dim3(32, 24), 256, 0, stream>>>(xb, wqb, wkb, wvb, Qb, Kb, Vb, 0);
  k_rope<<<8192, 256, 0, stream>>>(Qb, Kb);
  k_attn<<<dim3(32, 32), 256, 0, stream>>>(Qb, Kb, Vb, AO);
  k_gemm<<<dim3(32, 8), 256, 0, stream>>>(AO, wob, wob, wob, d_out, d_out, d_out, 1);
}